// Round 8
// baseline (227.063 us; speedup 1.0000x reference)
//
#include <hip/hip_runtime.h>
#include <stdint.h>

// Problem constants (fixed by reference)
#define BSZ 2
#define QL 2048
#define KVL 2048
#define NH 16
#define DQK 64
#define DM 1024

typedef __bf16 bf16x8 __attribute__((ext_vector_type(8)));
typedef float f32x4 __attribute__((ext_vector_type(4)));
typedef short short4v __attribute__((ext_vector_type(4)));

__device__ __forceinline__ ushort f2bf(float f) {
    union { float f; uint32_t u; } c; c.f = f;
    uint32_t u = c.u;
    return (ushort)((u + 0x7fffu + ((u >> 16) & 1u)) >> 16);
}

// pack two f32 -> two bf16 (round-half-up)
__device__ __forceinline__ uint32_t pack2bf(float lo, float hi) {
    union { float f; uint32_t u; } a, b;
    a.f = lo; b.f = hi;
    return __builtin_amdgcn_perm(b.u + 0x8000u, a.u + 0x8000u, 0x07060302u);
}

// truncating pack (P path: l is summed from the same bf16 P, so bias self-corrects)
__device__ __forceinline__ uint32_t pack2bf_t(float lo, float hi) {
    union { float f; uint32_t u; } a, b;
    a.f = lo; b.f = hi;
    return __builtin_amdgcn_perm(b.u, a.u, 0x07060302u);
}

// 16x16x16 bf16 MFMA (K=16): B-operand layout (n=lane&15, k=quad*4+j) matches the
// 16x16 C/D layout (col=lane&15, row=quad*4+reg) -> S^T accumulators feed PV directly.
__device__ __forceinline__ f32x4 mfma16(short4v a, short4v b, f32x4 c) {
#if __has_builtin(__builtin_amdgcn_mfma_f32_16x16x16bf16_1k)
    return __builtin_amdgcn_mfma_f32_16x16x16bf16_1k(a, b, c, 0, 0, 0);
#else
    asm volatile("v_mfma_f32_16x16x16_bf16 %0, %1, %2, %0"
                 : "+v"(c) : "v"(a), "v"(b));
    return c;
#endif
}

#define GLOAD_LDS16(g, l)                                              \
    __builtin_amdgcn_global_load_lds(                                  \
        (const __attribute__((address_space(1))) uint32_t*)(g),        \
        (__attribute__((address_space(3))) uint32_t*)(l), 16, 0, 0)

// ---------------- fused prep: rmsnorm (0..4095) + kv cast (4096..8191) + 3 transposes ----------------
__global__ __launch_bounds__(256) void prep_k(const float* __restrict__ qh_in,
                                              const float* __restrict__ lnw,
                                              ushort* __restrict__ normed,
                                              const float* __restrict__ kv_in,
                                              ushort* __restrict__ kvb,
                                              const float* __restrict__ w_q,
                                              const float* __restrict__ w_kv,
                                              const float* __restrict__ w_o,
                                              ushort* __restrict__ wqT,
                                              ushort* __restrict__ wkvT,
                                              ushort* __restrict__ woT) {
    int blk = blockIdx.x;
    int tid = threadIdx.x;
    if (blk < 4096) {
        int row = blk;
        const float4* xr = (const float4*)(qh_in + (size_t)row * DM);
        float4 v = xr[tid];
        float s = v.x * v.x + v.y * v.y + v.z * v.z + v.w * v.w;
#pragma unroll
        for (int off = 32; off > 0; off >>= 1) s += __shfl_down(s, off, 64);
        __shared__ float ws4[4];
        if ((tid & 63) == 0) ws4[tid >> 6] = s;
        __syncthreads();
        float tot = ws4[0] + ws4[1] + ws4[2] + ws4[3];
        float r = rsqrtf(tot * (1.0f / DM) + 1e-6f);
        float4 wv = ((const float4*)lnw)[tid];
        ushort4 o;
        o.x = f2bf(v.x * r * wv.x);
        o.y = f2bf(v.y * r * wv.y);
        o.z = f2bf(v.z * r * wv.z);
        o.w = f2bf(v.w * r * wv.w);
        ((ushort4*)(normed + (size_t)row * DM))[tid] = o;
        return;
    }
    if (blk < 8192) {
        int i = (blk - 4096) * 256 + tid;
        float4 v = ((const float4*)kv_in)[i];
        ushort4 r;
        r.x = f2bf(v.x); r.y = f2bf(v.y); r.z = f2bf(v.z); r.w = f2bf(v.w);
        ((ushort4*)kvb)[i] = r;
        return;
    }
    __shared__ ushort tile[64][65];
    int bi = blk - 8192;
    const float* in; ushort* out; int N, bx, by;
    const int K = 1024;
    if (bi < 256)      { in = w_q;  out = wqT;  N = 1024; bx = bi & 15; by = bi >> 4; }
    else if (bi < 768) { int j = bi - 256; in = w_kv; out = wkvT; N = 2048; bx = j & 31; by = j >> 5; }
    else               { int j = bi - 768; in = w_o;  out = woT;  N = 1024; bx = j & 15; by = j >> 4; }
    int k0 = by * 64, n0 = bx * 64;
    int colBase = tid & 63;
    int rowOff = tid >> 6;
#pragma unroll
    for (int i = 0; i < 16; ++i) {
        int row = i * 4 + rowOff;
        tile[colBase][row] = f2bf(in[(size_t)(k0 + row) * N + n0 + colBase]);
    }
    __syncthreads();
#pragma unroll
    for (int i = 0; i < 16; ++i) {
        int nrow = i * 4 + rowOff;
        out[(size_t)(n0 + nrow) * K + k0 + colBase] = tile[nrow][colBase];
    }
}

// ---------------- fused q-proj + kv-proj GEMM, 64x128 tiles (1536 blocks, 6/CU) ----------------
// grid (24, 64): bx 0..7 q (pre-scaled by log2e), 8..15 k, 16..23 v (transposed to vT).
// Epilogues via LDS transpose tiles -> coalesced b128 global stores.
__global__ __launch_bounds__(256) void gemm_qkv_k(
    const ushort* __restrict__ normed, const ushort* __restrict__ kvb,
    const ushort* __restrict__ wqT, const ushort* __restrict__ wkvT,
    ushort* __restrict__ q_out, ushort* __restrict__ k_out, ushort* __restrict__ vt_out) {
    __shared__ __align__(16) ushort smem[9216];  // staging 6144; epilogue q/k 64x136, v 128x72
    ushort* As = smem;            // 64 x 32
    ushort* Bs = smem + 2048;     // 128 x 32
    const int K = DM;
    int tid = threadIdx.x;
    int wave = tid >> 6, lane = tid & 63, quad = lane >> 4, l16 = lane & 15;
    int bx = blockIdx.x;
    int isQ = bx < 8;
    const ushort* A = isQ ? normed : kvb;
    const ushort* Bt = isQ ? wqT : wkvT;
    int n0 = (isQ ? bx : bx - 8) * 128;
    int m0 = blockIdx.y * 64;
    int wm = (wave & 1) * 32, wn = (wave >> 1) * 64;

    int r0 = tid >> 2, c0 = (tid & 3) << 3;
    const ushort* ga0 = &A[(size_t)(m0 + r0) * K + c0];
    const ushort* gb0 = &Bt[(size_t)(n0 + r0) * K + c0];

    f32x4 zero = {0.f, 0.f, 0.f, 0.f};
    f32x4 acc[2][4];
#pragma unroll
    for (int i = 0; i < 2; ++i)
#pragma unroll
        for (int j = 0; j < 4; ++j) acc[i][j] = zero;

    for (int k0 = 0; k0 < K; k0 += 32) {
        GLOAD_LDS16(ga0 + k0, &As[tid * 8]);
        GLOAD_LDS16(gb0 + k0, &Bs[tid * 8]);
        GLOAD_LDS16(gb0 + (size_t)64 * K + k0, &Bs[(tid + 256) * 8]);
        __syncthreads();
        bf16x8 af[2], bfr[4];
#pragma unroll
        for (int mi = 0; mi < 2; ++mi)
            af[mi] = *(const bf16x8*)(&As[(wm + mi * 16 + l16) * 32 + quad * 8]);
#pragma unroll
        for (int ni = 0; ni < 4; ++ni)
            bfr[ni] = *(const bf16x8*)(&Bs[(wn + ni * 16 + l16) * 32 + quad * 8]);
#pragma unroll
        for (int mi = 0; mi < 2; ++mi)
#pragma unroll
            for (int ni = 0; ni < 4; ++ni)
                acc[mi][ni] = __builtin_amdgcn_mfma_f32_16x16x32_bf16(
                    af[mi], bfr[ni], acc[mi][ni], 0, 0, 0);
        __syncthreads();
    }

    const float L2E = 1.44269504089f;
    int b = m0 >> 11, m0t = m0 & 2047;
    if (bx < 16) {
        // q/k: LDS tile [t 64][n 128] stride 136 (16B-aligned rows)
        float sc = isQ ? L2E : 1.0f;
        ushort* dst0 = isQ ? q_out : k_out;
#pragma unroll
        for (int mi = 0; mi < 2; ++mi) {
            int t_loc = wm + mi * 16 + quad * 4;
#pragma unroll
            for (int ni = 0; ni < 4; ++ni) {
                int n_loc = wn + ni * 16 + l16;
#pragma unroll
                for (int r = 0; r < 4; ++r) {
                    union { float f; uint32_t u; } c;
                    c.f = acc[mi][ni][r] * sc;
                    smem[(t_loc + r) * 136 + n_loc] = (ushort)((c.u + 0x8000u) >> 16);
                }
            }
        }
        __syncthreads();
        int hb = (n0 >> 6) & 15;
#pragma unroll
        for (int it = 0; it < 4; ++it) {
            int idx = it * 256 + tid;
            int t = idx >> 4, ch = (idx & 15) << 3;
            int h = hb + (ch >> 6), d = ch & 63;
            uint4 vv = *(const uint4*)&smem[t * 136 + ch];
            *(uint4*)&dst0[((size_t)((b << 4) | h) * QL + m0t + t) * DQK + d] = vv;
        }
    } else {
        // v: LDS tile [n 128][t 64] stride 72, uint2 writes, then b128 rows to vT
        int hbase = (n0 >> 6) & 15;
        int rbase = ((b << 4) | hbase) * 64;
#pragma unroll
        for (int mi = 0; mi < 2; ++mi) {
            int t_loc = wm + mi * 16 + quad * 4;
#pragma unroll
            for (int ni = 0; ni < 4; ++ni) {
                int n_loc = wn + ni * 16 + l16;
                uint2 pk;
                pk.x = pack2bf(acc[mi][ni][0], acc[mi][ni][1]);
                pk.y = pack2bf(acc[mi][ni][2], acc[mi][ni][3]);
                *(uint2*)&smem[n_loc * 72 + t_loc] = pk;
            }
        }
        __syncthreads();
#pragma unroll
        for (int it = 0; it < 4; ++it) {
            int idx = it * 256 + tid;
            int n = idx >> 3, ch = (idx & 7) << 3;
            uint4 vv = *(const uint4*)&smem[n * 72 + ch];
            *(uint4*)&vt_out[((size_t)(rbase + n)) * KVL + m0t + ch] = vv;
        }
    }
}

// ---------------- o-projection GEMM, 64x64 tile (1024 blocks, 4/CU) + residual ----------------
__global__ __launch_bounds__(256) void gemm_o_k(const ushort* __restrict__ A,
                                                const ushort* __restrict__ Bt,
                                                const float* __restrict__ resid,
                                                float* __restrict__ f_out) {
    __shared__ __align__(16) ushort As[64 * 32];
    __shared__ __align__(16) ushort Bs[64 * 32];
    const int K = DM;
    int tid = threadIdx.x;
    int wave = tid >> 6, lane = tid & 63, quad = lane >> 4, l16 = lane & 15;
    int n0 = blockIdx.x * 64, m0 = blockIdx.y * 64;
    int wm = (wave & 1) * 32, wn = (wave >> 1) * 32;

    int r0 = tid >> 2, c0 = (tid & 3) << 3;
    const ushort* ga0 = &A[(size_t)(m0 + r0) * K + c0];
    const ushort* gb0 = &Bt[(size_t)(n0 + r0) * K + c0];

    f32x4 zero = {0.f, 0.f, 0.f, 0.f};
    f32x4 acc[2][2];
#pragma unroll
    for (int i = 0; i < 2; ++i)
#pragma unroll
        for (int j = 0; j < 2; ++j) acc[i][j] = zero;

    for (int k0 = 0; k0 < K; k0 += 32) {
        GLOAD_LDS16(ga0 + k0, &As[tid * 8]);
        GLOAD_LDS16(gb0 + k0, &Bs[tid * 8]);
        __syncthreads();
        bf16x8 af[2], bfr[2];
#pragma unroll
        for (int mi = 0; mi < 2; ++mi)
            af[mi] = *(const bf16x8*)(&As[(wm + mi * 16 + l16) * 32 + quad * 8]);
#pragma unroll
        for (int ni = 0; ni < 2; ++ni)
            bfr[ni] = *(const bf16x8*)(&Bs[(wn + ni * 16 + l16) * 32 + quad * 8]);
#pragma unroll
        for (int mi = 0; mi < 2; ++mi)
#pragma unroll
            for (int ni = 0; ni < 2; ++ni)
                acc[mi][ni] = __builtin_amdgcn_mfma_f32_16x16x32_bf16(
                    af[mi], bfr[ni], acc[mi][ni], 0, 0, 0);
        __syncthreads();
    }

#pragma unroll
    for (int mi = 0; mi < 2; ++mi) {
#pragma unroll
        for (int ni = 0; ni < 2; ++ni) {
#pragma unroll
            for (int r = 0; r < 4; ++r) {
                int mm = m0 + wm + mi * 16 + quad * 4 + r;
                int nn = n0 + wn + ni * 16 + l16;
                size_t o = (size_t)mm * DM + nn;
                f_out[o] = resid[o] + acc[mi][ni][r];
            }
        }
    }
}

// ---------------- flash attention: P stays in registers (16x16x16 PV) ----------------
// grid (QL/128, B*NH), 256 thr; wave owns 2 groups of 16 q. S^T via 16x16x32; its C-layout
// IS the B-operand layout of 16x16x16 (k=t) -> PV and l-sum use packed P directly from
// registers. LDS only stages K and V^T (9216 ushorts). No P region, no P round-trip.
__global__ __launch_bounds__(256) void attn_k(const ushort* __restrict__ qh,
                                              const ushort* __restrict__ kh,
                                              const ushort* __restrict__ vt,
                                              ushort* __restrict__ ao) {
    __shared__ __align__(16) ushort smem[9216];
    ushort* Ks = smem;            // 64 x 72
    ushort* Vs = smem + 4608;     // 64 x 72  (V^T: [d][t])
    int bh = blockIdx.y, bI = bh >> 4, hI = bh & 15;
    int q0 = blockIdx.x * 128;
    int tid = threadIdx.x, wave = tid >> 6, lane = tid & 63;
    int quad = lane >> 4, l16 = lane & 15;
    const ushort* Qp = qh + (size_t)bh * QL * DQK;
    const ushort* Kp = kh + (size_t)bh * KVL * DQK;
    const ushort* Vp = vt + (size_t)bh * DQK * KVL;

    // Q fragments (B operand of 16x16x32), 2 groups of 16 q-columns per wave
    bf16x8 qf[2][2];
#pragma unroll
    for (int g = 0; g < 2; ++g) {
        const ushort* qrow = Qp + (size_t)(q0 + wave * 32 + g * 16 + l16) * DQK;
        qf[g][0] = *(const bf16x8*)(qrow + quad * 8);
        qf[g][1] = *(const bf16x8*)(qrow + 32 + quad * 8);
    }

    // ones A-fragment for 16x16x16: row 0 (lanes l16==0) = 1.0 -> C row0 = column sums
    short4v onef4;
#pragma unroll
    for (int j = 0; j < 4; ++j) onef4[j] = (l16 == 0) ? (short)0x3F80 : (short)0;

    int srow = tid >> 3;          // 0..31
    int scol = (tid & 7) << 3;    // 0..56

    f32x4 zero = {0.f, 0.f, 0.f, 0.f};
    f32x4 o[2][4];
    f32x4 lacc[2];
#pragma unroll
    for (int g = 0; g < 2; ++g) {
        lacc[g] = zero;
#pragma unroll
        for (int i = 0; i < 4; ++i) o[g][i] = zero;
    }

    // prefetch tile 0
    uint4 kr0 = *(const uint4*)&Kp[(size_t)srow * DQK + scol];
    uint4 kr1 = *(const uint4*)&Kp[(size_t)(srow + 32) * DQK + scol];
    uint4 vr0 = *(const uint4*)&Vp[(size_t)srow * KVL + scol];
    uint4 vr1 = *(const uint4*)&Vp[(size_t)(srow + 32) * KVL + scol];

    for (int t0 = 0; t0 < KVL; t0 += 64) {
        *(uint4*)&Ks[srow * 72 + scol] = kr0;
        *(uint4*)&Ks[(srow + 32) * 72 + scol] = kr1;
        *(uint4*)&Vs[srow * 72 + scol] = vr0;
        *(uint4*)&Vs[(srow + 32) * 72 + scol] = vr1;
        __syncthreads();
        int tn = t0 + 64;
        if (tn < KVL) {
            kr0 = *(const uint4*)&Kp[(size_t)(tn + srow) * DQK + scol];
            kr1 = *(const uint4*)&Kp[(size_t)(tn + srow + 32) * DQK + scol];
            vr0 = *(const uint4*)&Vp[(size_t)srow * KVL + tn + scol];
            vr1 = *(const uint4*)&Vp[(size_t)(srow + 32) * KVL + tn + scol];
        }

        // V^T A-fragments for 16x16x16: vf[ni][mi] = V^T[d=ni*16+l16][t=mi*16+quad*4 ..+3]
        short4v vf[4][4];
#pragma unroll
        for (int ni = 0; ni < 4; ++ni)
#pragma unroll
            for (int mi = 0; mi < 4; ++mi)
                vf[ni][mi] = *(const short4v*)&Vs[(ni * 16 + l16) * 72 + mi * 16 + quad * 4];

        // S^T[t][q] = K·Q^T; K-frag loaded once, used for both q-groups
        f32x4 s[2][4];
#pragma unroll
        for (int mi = 0; mi < 4; ++mi) {
            const ushort* kb = &Ks[(mi * 16 + l16) * 72 + quad * 8];
            bf16x8 kf0 = *(const bf16x8*)kb;
            bf16x8 kf1 = *(const bf16x8*)(kb + 32);
#pragma unroll
            for (int g = 0; g < 2; ++g) {
                f32x4 a = zero;
                a = __builtin_amdgcn_mfma_f32_16x16x32_bf16(kf0, qf[g][0], a, 0, 0, 0);
                a = __builtin_amdgcn_mfma_f32_16x16x32_bf16(kf1, qf[g][1], a, 0, 0, 0);
                s[g][mi] = a;
            }
        }

        // p = exp2(s); pack in registers (C-layout == 16x16x16 B-layout, k=t);
        // l via ones-row 16x16x16; O^T += V^T·P^T via 16x16x16, all P from registers.
#pragma unroll
        for (int g = 0; g < 2; ++g) {
#pragma unroll
            for (int mi = 0; mi < 4; ++mi)
#pragma unroll
                for (int r = 0; r < 4; ++r)
                    s[g][mi][r] = __builtin_amdgcn_exp2f(s[g][mi][r]);
            short4v pb[4];
#pragma unroll
            for (int mi = 0; mi < 4; ++mi) {
                union { uint2 u; short4v s4; } pk;
                pk.u.x = pack2bf_t(s[g][mi][0], s[g][mi][1]);
                pk.u.y = pack2bf_t(s[g][mi][2], s[g][mi][3]);
                pb[mi] = pk.s4;
            }
#pragma unroll
            for (int mi = 0; mi < 4; ++mi)
                lacc[g] = mfma16(onef4, pb[mi], lacc[g]);
#pragma unroll
            for (int ni = 0; ni < 4; ++ni)
#pragma unroll
                for (int mi = 0; mi < 4; ++mi)
                    o[g][ni] = mfma16(vf[ni][mi], pb[mi], o[g][ni]);
        }
        __syncthreads();
    }

    // epilogue: l in (quad0, reg0); 2 shfl-adds broadcast. O^T -> O via LDS, b128 stores.
#pragma unroll
    for (int g = 0; g < 2; ++g) {
        float lg = lacc[g][0];
        lg += __shfl_xor(lg, 16, 64);
        lg += __shfl_xor(lg, 32, 64);
        float rinv = __builtin_amdgcn_rcpf(lg);
        ushort* orow = &smem[(size_t)(wave * 32 + g * 16 + l16) * 72];
#pragma unroll
        for (int mi = 0; mi < 4; ++mi) {
            uint2 pk;
            pk.x = pack2bf(o[g][mi][0] * rinv, o[g][mi][1] * rinv);
            pk.y = pack2bf(o[g][mi][2] * rinv, o[g][mi][3] * rinv);
            *(uint2*)&orow[mi * 16 + quad * 4] = pk;
        }
    }
    __syncthreads();
#pragma unroll
    for (int it = 0; it < 4; ++it) {
        int idx = tid + it * 256;
        int ql = idx >> 3, c = (idx & 7) << 3;
        uint4 vv = *(const uint4*)&smem[ql * 72 + c];
        *(uint4*)&ao[((size_t)(bI * QL + q0 + ql)) * DM + hI * 64 + c] = vv;
    }
}

extern "C" void kernel_launch(void* const* d_in, const int* in_sizes, int n_in,
                              void* d_out, int out_size, void* d_ws, size_t ws_size,
                              hipStream_t stream) {
    (void)in_sizes; (void)n_in; (void)out_size; (void)ws_size;
    const float* qh_in = (const float*)d_in[0];
    const float* kv_in = (const float*)d_in[2];
    const float* w_q  = (const float*)d_in[4];
    const float* w_kv = (const float*)d_in[5];
    const float* w_o  = (const float*)d_in[6];
    const float* lnw  = (const float*)d_in[7];
    float* out = (float*)d_out;

    char* ws = (char*)d_ws;
    ushort* normed = (ushort*)(ws);                        // 8 MB
    ushort* kvb    = (ushort*)(ws + ((size_t)8 << 20));    // 8 MB
    ushort* wqT    = (ushort*)(ws + ((size_t)16 << 20));   // 2 MB
    ushort* wkvT   = (ushort*)(ws + ((size_t)18 << 20));   // 4 MB
    ushort* woT    = (ushort*)(ws + ((size_t)22 << 20));   // 2 MB
    ushort* qheads = (ushort*)(ws + ((size_t)24 << 20));   // 8 MB  [bh][q][d] (pre-scaled log2e)
    ushort* kheads = (ushort*)(ws + ((size_t)32 << 20));   // 8 MB  [bh][t][d]
    ushort* vT     = (ushort*)(ws + ((size_t)40 << 20));   // 8 MB  [bh*64+d][t]
    ushort* attno  = (ushort*)(ws + ((size_t)48 << 20));   // 8 MB  [b*q][1024]

    prep_k<<<9216, 256, 0, stream>>>(qh_in, lnw, normed, kv_in, kvb,
                                     w_q, w_kv, w_o, wqT, wkvT, woT);
    gemm_qkv_k<<<dim3(24, 64), 256, 0, stream>>>(normed, kvb, wqT, wkvT,
                                                 qheads, kheads, vT);
    attn_k<<<dim3(QL / 128, BSZ * NH), 256, 0, stream>>>(qheads, kheads, vT, attno);
    gemm_o_k<<<dim3(16, 64), 256, 0, stream>>>(attno, woT, qh_in, out);
}